// Round 5
// baseline (133.557 us; speedup 1.0000x reference)
//
#include <hip/hip_runtime.h>

#define H_ 200
#define W_ 200
#define DELX_ 1.5f
#define DELY_ 1.5f
#define NXV_ 256
#define NYV_ 256
#define NZV_ 256
#define EPS_ 1e-8f
#define NSEG 8
#define PPB 32            // pixels per block (block = PPB * NSEG = 256 threads)
#define TILE_R 8          // detector tile rows  (8x4 = 32 pixels)
#define TILE_C 4
#define TILES_PER_IMG ((H_ / TILE_R) * (W_ / TILE_C))   // 25*50 = 1250
#define G_ 8              // steps marched per group (loads in flight)
#define MAXGG 7           // 7 double-groups = 14 groups = 112 steps >= 101 worst case

// alpha for integer plane k, via multiply by precomputed reciprocal (no divide)
__device__ __forceinline__ float alpha_mul(float k, float sp, float src, float inv_sdd) {
    return (k * sp - src) * inv_sdd;
}

__global__ void __launch_bounds__(256)
drr_fused(const float* __restrict__ vol,
          const float* __restrict__ spacing,
          const float* __restrict__ sdr,
          const float* __restrict__ rot,
          const float* __restrict__ trans,
          float* __restrict__ out) {
    const int t = threadIdx.x;
    const int pixLocal = t & (PPB - 1);     // 0..31
    const int seg = t >> 5;                 // 0..7 ; wave = 32 px x 2 adjacent segs

    // 2D detector tiling: 8x4 pixel patch per 32-pixel group
    const int b   = blockIdx.x / TILES_PER_IMG;
    const int rem = blockIdx.x % TILES_PER_IMG;
    const int ty  = rem / (W_ / TILE_C);
    const int tx  = rem % (W_ / TILE_C);
    const int i = ty * TILE_R + (pixLocal >> 2);
    const int j = tx * TILE_C + (pixLocal & 3);

    // --- rotation matrix R = Rz(theta) Ry(phi) Rx(gamma) ---
    const float theta = rot[b * 3 + 0], phi = rot[b * 3 + 1], gamma = rot[b * 3 + 2];
    const float ct = cosf(theta), st = sinf(theta);
    const float cp = cosf(phi),   sp = sinf(phi);
    const float cg = cosf(gamma), sg = sinf(gamma);
    const float r00 = ct * cp,                r10 = st * cp,                r20 = -sp;
    const float r01 = ct * sp * sg - st * cg, r11 = st * sp * sg + ct * cg, r21 = cp * sg;
    const float r02 = ct * sp * cg + st * sg, r12 = st * sp * cg - ct * sg, r22 = cp * cg;

    const float sd = sdr[b];
    const float tx_ = trans[b * 3 + 0], ty_ = trans[b * 3 + 1], tz_ = trans[b * 3 + 2];
    const float sx = sd * r00 + tx_, sy = sd * r10 + ty_, sz = sd * r20 + tz_;
    const float cxx = -sd * r00 + tx_, cyy = -sd * r10 + ty_, czz = -sd * r20 + tz_;

    const float tco = ((float)(i - H_ / 2) + 1.0f) * DELX_;
    const float sco = ((float)(j - W_ / 2) + 1.0f) * DELY_;
    const float gx = r01 * tco + r02 * sco + cxx;
    const float gy = r11 * tco + r12 * sco + cyy;
    const float gz = r21 * tco + r22 * sco + czz;

    const float dx = gx - sx + EPS_;
    const float dy = gy - sy + EPS_;
    const float dz = gz - sz + EPS_;

    const float spx = spacing[0], spy = spacing[1], spz = spacing[2];
    const float inv_spx = 1.0f / spx, inv_spy = 1.0f / spy, inv_spz = 1.0f / spz;
    const float inv_dx = 1.0f / dx, inv_dy = 1.0f / dy, inv_dz = 1.0f / dz;

    const float a0x = alpha_mul(0.f, spx, sx, inv_dx), a1x = alpha_mul((float)NXV_, spx, sx, inv_dx);
    const float a0y = alpha_mul(0.f, spy, sy, inv_dy), a1y = alpha_mul((float)NYV_, spy, sy, inv_dy);
    const float a0z = alpha_mul(0.f, spz, sz, inv_dz), a1z = alpha_mul((float)NZV_, spz, sz, inv_dz);

    const float amin = fmaxf(fmaxf(fminf(a0x, a1x), fminf(a0y, a1y)), fminf(a0z, a1z));
    const float amax = fminf(fminf(fmaxf(a0x, a1x), fmaxf(a0y, a1y)), fmaxf(a0z, a1z));

    const float norm = sqrtf(dx * dx + dy * dy + dz * dz);

    // segment bounds at x-plane crossings (exact members of the crossing set;
    // identical formula across segments -> bitwise-consistent partition)
    const float klo = (float)(seg * (NXV_ / NSEG));
    const float khi = (float)((seg + 1) * (NXV_ / NSEG));
    const float aA = alpha_mul(klo, spx, sx, inv_dx);
    const float aB = alpha_mul(khi, spx, sx, inv_dx);
    const float lo = fminf(aA, aB), hi = fmaxf(aA, aB);

    const float start = fmaxf(amin, lo);
    const float end   = fminf(amax, hi);

    float acc = 0.0f;
    if (start < end) {
        float kx, ky, kz, axv, ayv, azv, dkx, dky, dkz;
        {
            float kf = (start * dx + sx) * inv_spx;
            if (dx > 0.f) { dkx = 1.f;  kx = floorf(kf) + 1.f; }
            else          { dkx = -1.f; kx = ceilf(kf) - 1.f; }
            axv = alpha_mul(kx, spx, sx, inv_dx);
        }
        {
            float kf = (start * dy + sy) * inv_spy;
            if (dy > 0.f) { dky = 1.f;  ky = floorf(kf) + 1.f; }
            else          { dky = -1.f; ky = ceilf(kf) - 1.f; }
            ayv = alpha_mul(ky, spy, sy, inv_dy);
        }
        {
            float kf = (start * dz + sz) * inv_spz;
            if (dz > 0.f) { dkz = 1.f;  kz = floorf(kf) + 1.f; }
            else          { dkz = -1.f; kz = ceilf(kf) - 1.f; }
            azv = alpha_mul(kz, spz, sz, inv_dz);
        }

        float a_cur = start;

        // march G_ steps: fill stp/off arrays, return alpha of last step.
        // Math is bitwise-identical to R4's inner loop.
        auto march8 = [&](float* stp, int* off) -> float {
            float an_l = a_cur;
            #pragma unroll
            for (int u = 0; u < G_; ++u) {
                float an = fminf(axv, fminf(ayv, azv));
                bool ok = (an <= end);
                stp[u] = ok ? (an - a_cur) : 0.0f;
                float midv = 0.5f * (a_cur + an);
                float x = (sx + midv * dx) * inv_spx;
                float y = (sy + midv * dy) * inv_spy;
                float z = (sz + midv * dz) * inv_spz;
                int ix = (int)x;   // trunc toward zero, matches jnp.trunc->int32
                int iy = (int)y;
                int iz = (int)z;
                ix = min(max(ix, 0), NXV_ - 1);
                iy = min(max(iy, 0), NYV_ - 1);
                iz = min(max(iz, 0), NZV_ - 1);
                off[u] = ((NXV_ - 1 - ix) * NYV_ + iy) * NZV_ + iz;  // flip axis 0
                a_cur = an;
                bool cx = (axv == an), cy = (ayv == an), cz = (azv == an);
                kx = cx ? kx + dkx : kx;
                ky = cy ? ky + dky : ky;
                kz = cz ? kz + dkz : kz;
                axv = alpha_mul(kx, spx, sx, inv_dx);  // bitwise-stable recompute
                ayv = alpha_mul(ky, spy, sy, inv_dy);
                azv = alpha_mul(kz, spz, sz, inv_dz);
                an_l = an;
            }
            return an_l;
        };

        float stpA[G_], stpB[G_];
        int   offA[G_], offB[G_];
        float vA[G_], vB[G_];

        float anA = march8(stpA, offA);
        float anB;

        // software pipeline: issue loads for current group, march next group
        // while they are in flight, then consume. Double-buffered (no copies).
        for (int gg = 0; gg < MAXGG; ++gg) {
            // ---- phase 1: consume A, prefetch-march B ----
            #pragma unroll
            for (int u = 0; u < G_; ++u) vA[u] = vol[offA[u]];   // 8 loads in flight
            bool doneA = anA > end;
            anB = march8(stpB, offB);                             // overlaps load latency
            #pragma unroll
            for (int u = 0; u < G_; ++u) acc += vA[u] * stpA[u];
            if (doneA) break;

            // ---- phase 2: consume B, prefetch-march A ----
            #pragma unroll
            for (int u = 0; u < G_; ++u) vB[u] = vol[offB[u]];
            bool doneB = anB > end;
            anA = march8(stpA, offA);
            #pragma unroll
            for (int u = 0; u < G_; ++u) acc += vB[u] * stpB[u];
            if (doneB) break;
        }
    }
    float result = acc * norm;

    // block-level reduce: NSEG segments per pixel, fixed k-order summation
    __shared__ float red[NSEG * PPB];
    red[t] = result;
    __syncthreads();
    if (t < PPB) {
        const int ii = ty * TILE_R + (t >> 2);
        const int jj = tx * TILE_C + (t & 3);
        const int opix = b * (H_ * W_) + ii * W_ + jj;
        float s = 0.0f;
        #pragma unroll
        for (int k = 0; k < NSEG; k++) s += red[t + k * PPB];
        out[opix] = s;
    }
}

extern "C" void kernel_launch(void* const* d_in, const int* in_sizes, int n_in,
                              void* d_out, int out_size, void* d_ws, size_t ws_size,
                              hipStream_t stream) {
    const float* vol     = (const float*)d_in[0];
    const float* spacing = (const float*)d_in[1];
    const float* sdr     = (const float*)d_in[2];
    const float* rot     = (const float*)d_in[3];
    const float* trans   = (const float*)d_in[4];
    float* out = (float*)d_out;

    const int B = in_sizes[2];
    const int nblocks = B * TILES_PER_IMG;
    drr_fused<<<nblocks, NSEG * PPB, 0, stream>>>(vol, spacing, sdr, rot, trans, out);
}

// Round 6
// 120.613 us; speedup vs baseline: 1.1073x; 1.1073x over previous
//
#include <hip/hip_runtime.h>

#define H_ 200
#define W_ 200
#define DELX_ 1.5f
#define DELY_ 1.5f
#define NXV_ 256
#define NYV_ 256
#define NZV_ 256
#define EPS_ 1e-8f
#define NSEG 16           // x-slabs of 16 planes each
#define SEGS_PER_BLK 8    // block = 64 px * 8 segs = 512 threads; 2 blocks/tile
#define TILE_R 8          // 8x8 detector patch = 64 px = one wave per seg
#define TILE_C 8
#define TILES_PER_IMG ((H_ / TILE_R) * (W_ / TILE_C))   // 25*25 = 625
#define G_ 8              // steps marched per group (loads in flight)
#define MAXG 10           // 10 groups * 8 = 80 steps >= worst-case per 16-slab

// alpha for integer plane k, via multiply by precomputed reciprocal (no divide)
__device__ __forceinline__ float alpha_mul(float k, float sp, float src, float inv_sdd) {
    return (k * sp - src) * inv_sdd;
}

__global__ void __launch_bounds__(512, 8)
drr_partial(const float* __restrict__ vol,
            const float* __restrict__ spacing,
            const float* __restrict__ sdr,
            const float* __restrict__ rot,
            const float* __restrict__ trans,
            float* __restrict__ partials,
            int npix) {
    const int t = threadIdx.x;
    const int pixLocal = t & 63;            // 0..63 : full 8x8 patch per wave
    const int half = blockIdx.x & 1;        // seg-half of this block
    const int seg = (t >> 6) + (half << 3); // 0..15 ; wave = 64 px x 1 slab
    const int tileBlk = blockIdx.x >> 1;

    const int b    = tileBlk / TILES_PER_IMG;
    const int rem  = tileBlk % TILES_PER_IMG;
    const int ty   = rem / (W_ / TILE_C);
    const int tx   = rem % (W_ / TILE_C);
    const int i = ty * TILE_R + (pixLocal >> 3);
    const int j = tx * TILE_C + (pixLocal & 7);

    // --- rotation matrix R = Rz(theta) Ry(phi) Rx(gamma) ---
    const float theta = rot[b * 3 + 0], phi = rot[b * 3 + 1], gamma = rot[b * 3 + 2];
    const float ct = cosf(theta), st = sinf(theta);
    const float cp = cosf(phi),   sp = sinf(phi);
    const float cg = cosf(gamma), sg = sinf(gamma);
    const float r00 = ct * cp,                r10 = st * cp,                r20 = -sp;
    const float r01 = ct * sp * sg - st * cg, r11 = st * sp * sg + ct * cg, r21 = cp * sg;
    const float r02 = ct * sp * cg + st * sg, r12 = st * sp * cg - ct * sg, r22 = cp * cg;

    const float sd = sdr[b];
    const float tx_ = trans[b * 3 + 0], ty_ = trans[b * 3 + 1], tz_ = trans[b * 3 + 2];
    const float sx = sd * r00 + tx_, sy = sd * r10 + ty_, sz = sd * r20 + tz_;
    const float cxx = -sd * r00 + tx_, cyy = -sd * r10 + ty_, czz = -sd * r20 + tz_;

    const float tco = ((float)(i - H_ / 2) + 1.0f) * DELX_;
    const float sco = ((float)(j - W_ / 2) + 1.0f) * DELY_;
    const float gx = r01 * tco + r02 * sco + cxx;
    const float gy = r11 * tco + r12 * sco + cyy;
    const float gz = r21 * tco + r22 * sco + czz;

    const float dx = gx - sx + EPS_;
    const float dy = gy - sy + EPS_;
    const float dz = gz - sz + EPS_;

    const float spx = spacing[0], spy = spacing[1], spz = spacing[2];
    const float inv_spx = 1.0f / spx, inv_spy = 1.0f / spy, inv_spz = 1.0f / spz;
    const float inv_dx = 1.0f / dx, inv_dy = 1.0f / dy, inv_dz = 1.0f / dz;

    const float a0x = alpha_mul(0.f, spx, sx, inv_dx), a1x = alpha_mul((float)NXV_, spx, sx, inv_dx);
    const float a0y = alpha_mul(0.f, spy, sy, inv_dy), a1y = alpha_mul((float)NYV_, spy, sy, inv_dy);
    const float a0z = alpha_mul(0.f, spz, sz, inv_dz), a1z = alpha_mul((float)NZV_, spz, sz, inv_dz);

    const float amin = fmaxf(fmaxf(fminf(a0x, a1x), fminf(a0y, a1y)), fminf(a0z, a1z));
    const float amax = fminf(fminf(fmaxf(a0x, a1x), fmaxf(a0y, a1y)), fmaxf(a0z, a1z));

    const float norm = sqrtf(dx * dx + dy * dy + dz * dz);

    // segment bounds at x-plane crossings (exact members of the crossing set;
    // identical formula across segments -> bitwise-consistent partition)
    const float klo = (float)(seg * (NXV_ / NSEG));
    const float khi = (float)((seg + 1) * (NXV_ / NSEG));
    const float aA = alpha_mul(klo, spx, sx, inv_dx);
    const float aB = alpha_mul(khi, spx, sx, inv_dx);
    const float lo = fminf(aA, aB), hi = fmaxf(aA, aB);

    const float start = fmaxf(amin, lo);
    const float end   = fminf(amax, hi);

    float acc = 0.0f;
    if (start < end) {
        float kx, ky, kz, axv, ayv, azv, dkx, dky, dkz;
        {
            float kf = (start * dx + sx) * inv_spx;
            if (dx > 0.f) { dkx = 1.f;  kx = floorf(kf) + 1.f; }
            else          { dkx = -1.f; kx = ceilf(kf) - 1.f; }
            axv = alpha_mul(kx, spx, sx, inv_dx);
        }
        {
            float kf = (start * dy + sy) * inv_spy;
            if (dy > 0.f) { dky = 1.f;  ky = floorf(kf) + 1.f; }
            else          { dky = -1.f; ky = ceilf(kf) - 1.f; }
            ayv = alpha_mul(ky, spy, sy, inv_dy);
        }
        {
            float kf = (start * dz + sz) * inv_spz;
            if (dz > 0.f) { dkz = 1.f;  kz = floorf(kf) + 1.f; }
            else          { dkz = -1.f; kz = ceilf(kf) - 1.f; }
            azv = alpha_mul(kz, spz, sz, inv_dz);
        }

        float a_cur = start;
        // groups of G_ steps: march G_ (addresses+steps), then G_ loads in flight
        for (int g = 0; g < MAXG; ++g) {
            float stp[G_];
            int   off[G_];
            float an_last;
            #pragma unroll
            for (int u = 0; u < G_; ++u) {
                float an = fminf(axv, fminf(ayv, azv));
                bool ok = (an <= end);
                stp[u] = ok ? (an - a_cur) : 0.0f;
                float midv = 0.5f * (a_cur + an);
                float x = (sx + midv * dx) * inv_spx;
                float y = (sy + midv * dy) * inv_spy;
                float z = (sz + midv * dz) * inv_spz;
                int ix = (int)x;   // trunc toward zero, matches jnp.trunc->int32
                int iy = (int)y;
                int iz = (int)z;
                ix = min(max(ix, 0), NXV_ - 1);
                iy = min(max(iy, 0), NYV_ - 1);
                iz = min(max(iz, 0), NZV_ - 1);
                off[u] = ((NXV_ - 1 - ix) * NYV_ + iy) * NZV_ + iz;  // flip axis 0
                a_cur = an;
                bool cx = (axv == an), cy = (ayv == an), cz = (azv == an);
                kx = cx ? kx + dkx : kx;
                ky = cy ? ky + dky : ky;
                kz = cz ? kz + dkz : kz;
                axv = alpha_mul(kx, spx, sx, inv_dx);  // bitwise-stable recompute
                ayv = alpha_mul(ky, spy, sy, inv_dy);
                azv = alpha_mul(kz, spz, sz, inv_dz);
                an_last = an;
            }
            float v[G_];
            #pragma unroll
            for (int u = 0; u < G_; ++u) v[u] = vol[off[u]];
            #pragma unroll
            for (int u = 0; u < G_; ++u) acc += v[u] * stp[u];
            if (an_last > end) break;
        }
    }
    float result = acc * norm;

    // block-level reduce over the 8 segs of this half, fixed k-order summation
    __shared__ float red[SEGS_PER_BLK * 64];
    red[t] = result;
    __syncthreads();
    if (t < 64) {
        const int ii = ty * TILE_R + (t >> 3);
        const int jj = tx * TILE_C + (t & 7);
        const int opix = b * (H_ * W_) + ii * W_ + jj;
        float s = 0.0f;
        #pragma unroll
        for (int k = 0; k < SEGS_PER_BLK; k++) s += red[t + k * 64];
        partials[(size_t)half * npix + opix] = s;
    }
}

__global__ void __launch_bounds__(256)
drr_combine(const float* __restrict__ partials, float* __restrict__ out, int npix) {
    int pix = blockIdx.x * blockDim.x + threadIdx.x;
    if (pix >= npix) return;
    out[pix] = partials[pix] + partials[(size_t)npix + pix];  // segs 0-7 then 8-15
}

extern "C" void kernel_launch(void* const* d_in, const int* in_sizes, int n_in,
                              void* d_out, int out_size, void* d_ws, size_t ws_size,
                              hipStream_t stream) {
    const float* vol     = (const float*)d_in[0];
    const float* spacing = (const float*)d_in[1];
    const float* sdr     = (const float*)d_in[2];
    const float* rot     = (const float*)d_in[3];
    const float* trans   = (const float*)d_in[4];
    float* out = (float*)d_out;

    const int B = in_sizes[2];
    const int npix = B * H_ * W_;
    float* partials = (float*)d_ws;     // 2 * npix floats

    const int nblocks = B * TILES_PER_IMG * 2;
    drr_partial<<<nblocks, 64 * SEGS_PER_BLK, 0, stream>>>(vol, spacing, sdr, rot, trans, partials, npix);
    drr_combine<<<(npix + 255) / 256, 256, 0, stream>>>(partials, out, npix);
}

// Round 7
// 118.271 us; speedup vs baseline: 1.1292x; 1.0198x over previous
//
#include <hip/hip_runtime.h>

#define H_ 200
#define W_ 200
#define DELX_ 1.5f
#define DELY_ 1.5f
#define NXV_ 256
#define NYV_ 256
#define NZV_ 256
#define EPS_ 1e-8f
#define NSEG 16           // x-slabs of 16 planes each
#define SEGS_PER_BLK 8    // block = 64 px * 8 segs = 512 threads; 2 blocks/tile
#define TILE_R 8          // 8x8 detector patch = 64 px = one wave per seg
#define TILE_C 8
#define TILES_PER_IMG ((H_ / TILE_R) * (W_ / TILE_C))   // 25*25 = 625
#define G_ 8              // steps marched per group (loads in flight)
#define MAXG 10           // 10 groups * 8 = 80 steps >= worst-case per 16-slab

// alpha for integer plane k, via multiply by precomputed reciprocal (no divide)
__device__ __forceinline__ float alpha_mul(float k, float sp, float src, float inv_sdd) {
    return (k * sp - src) * inv_sdd;
}

__global__ void __launch_bounds__(512, 8)
drr_partial(const float* __restrict__ vol,
            const float* __restrict__ spacing,
            const float* __restrict__ sdr,
            const float* __restrict__ rot,
            const float* __restrict__ trans,
            float* __restrict__ partials,
            int npix) {
    const int t = threadIdx.x;
    const int pixLocal = t & 63;            // 0..63 : full 8x8 patch per wave
    const int half = blockIdx.x & 1;        // seg-half of this block
    const int seg = (t >> 6) + (half << 3); // 0..15 ; wave = 64 px x 1 slab
    const int tileBlk = blockIdx.x >> 1;

    const int b    = tileBlk / TILES_PER_IMG;
    const int rem  = tileBlk % TILES_PER_IMG;
    const int ty   = rem / (W_ / TILE_C);
    const int tx   = rem % (W_ / TILE_C);
    const int i = ty * TILE_R + (pixLocal >> 3);
    const int j = tx * TILE_C + (pixLocal & 7);

    // --- rotation matrix R = Rz(theta) Ry(phi) Rx(gamma) ---
    const float theta = rot[b * 3 + 0], phi = rot[b * 3 + 1], gamma = rot[b * 3 + 2];
    const float ct = cosf(theta), st = sinf(theta);
    const float cp = cosf(phi),   sp = sinf(phi);
    const float cg = cosf(gamma), sg = sinf(gamma);
    const float r00 = ct * cp,                r10 = st * cp,                r20 = -sp;
    const float r01 = ct * sp * sg - st * cg, r11 = st * sp * sg + ct * cg, r21 = cp * sg;
    const float r02 = ct * sp * cg + st * sg, r12 = st * sp * cg - ct * sg, r22 = cp * cg;

    const float sd = sdr[b];
    const float tx_ = trans[b * 3 + 0], ty_ = trans[b * 3 + 1], tz_ = trans[b * 3 + 2];
    const float sx = sd * r00 + tx_, sy = sd * r10 + ty_, sz = sd * r20 + tz_;
    const float cxx = -sd * r00 + tx_, cyy = -sd * r10 + ty_, czz = -sd * r20 + tz_;

    const float tco = ((float)(i - H_ / 2) + 1.0f) * DELX_;
    const float sco = ((float)(j - W_ / 2) + 1.0f) * DELY_;
    const float gx = r01 * tco + r02 * sco + cxx;
    const float gy = r11 * tco + r12 * sco + cyy;
    const float gz = r21 * tco + r22 * sco + czz;

    const float dx = gx - sx + EPS_;
    const float dy = gy - sy + EPS_;
    const float dz = gz - sz + EPS_;

    const float spx = spacing[0], spy = spacing[1], spz = spacing[2];
    const float inv_spx = 1.0f / spx, inv_spy = 1.0f / spy, inv_spz = 1.0f / spz;
    const float inv_dx = 1.0f / dx, inv_dy = 1.0f / dy, inv_dz = 1.0f / dz;

    const float a0x = alpha_mul(0.f, spx, sx, inv_dx), a1x = alpha_mul((float)NXV_, spx, sx, inv_dx);
    const float a0y = alpha_mul(0.f, spy, sy, inv_dy), a1y = alpha_mul((float)NYV_, spy, sy, inv_dy);
    const float a0z = alpha_mul(0.f, spz, sz, inv_dz), a1z = alpha_mul((float)NZV_, spz, sz, inv_dz);

    const float amin = fmaxf(fmaxf(fminf(a0x, a1x), fminf(a0y, a1y)), fminf(a0z, a1z));
    const float amax = fminf(fminf(fmaxf(a0x, a1x), fmaxf(a0y, a1y)), fmaxf(a0z, a1z));

    const float norm = sqrtf(dx * dx + dy * dy + dz * dz);

    // segment bounds at x-plane crossings (exact members of the crossing set;
    // identical formula across segments -> bitwise-consistent partition)
    const float klo = (float)(seg * (NXV_ / NSEG));
    const float khi = (float)((seg + 1) * (NXV_ / NSEG));
    const float aA = alpha_mul(klo, spx, sx, inv_dx);
    const float aB = alpha_mul(khi, spx, sx, inv_dx);
    const float lo = fminf(aA, aB), hi = fmaxf(aA, aB);

    const float start = fmaxf(amin, lo);
    const float end   = fminf(amax, hi);

    float acc = 0.0f;
    if (start < end) {
        float kx, ky, kz, axv, ayv, azv, dkx, dky, dkz;
        {
            float kf = (start * dx + sx) * inv_spx;
            if (dx > 0.f) { dkx = 1.f;  kx = floorf(kf) + 1.f; }
            else          { dkx = -1.f; kx = ceilf(kf) - 1.f; }
            axv = alpha_mul(kx, spx, sx, inv_dx);
        }
        {
            float kf = (start * dy + sy) * inv_spy;
            if (dy > 0.f) { dky = 1.f;  ky = floorf(kf) + 1.f; }
            else          { dky = -1.f; ky = ceilf(kf) - 1.f; }
            ayv = alpha_mul(ky, spy, sy, inv_dy);
        }
        {
            float kf = (start * dz + sz) * inv_spz;
            if (dz > 0.f) { dkz = 1.f;  kz = floorf(kf) + 1.f; }
            else          { dkz = -1.f; kz = ceilf(kf) - 1.f; }
            azv = alpha_mul(kz, spz, sz, inv_dz);
        }

        // --- incremental cell walk: init cell from first interval midpoint,
        // then bump a single linear offset by the crossed axis's delta.
        // Cell stays in-bounds because updates stop once an >= end (exit-face
        // crossing is suppressed); initial cell clamped once for safety.
        int off_cur;
        {
            float an0 = fminf(axv, fminf(ayv, azv));
            float midv = 0.5f * (start + an0);
            int ix = (int)((sx + midv * dx) * inv_spx);   // trunc, matches ref
            int iy = (int)((sy + midv * dy) * inv_spy);
            int iz = (int)((sz + midv * dz) * inv_spz);
            ix = min(max(ix, 0), NXV_ - 1);
            iy = min(max(iy, 0), NYV_ - 1);
            iz = min(max(iz, 0), NZV_ - 1);
            off_cur = ((NXV_ - 1 - ix) * NYV_ + iy) * NZV_ + iz;  // flip axis 0
        }
        const int doffx = (dkx > 0.f) ? -(NYV_ * NZV_) : (NYV_ * NZV_);  // flipped x
        const int doffy = (dky > 0.f) ? NZV_ : -NZV_;
        const int doffz = (dkz > 0.f) ? 1 : -1;

        float a_cur = start;
        // groups of G_ steps: march G_ (offsets+steps), then G_ loads in flight
        for (int g = 0; g < MAXG; ++g) {
            float stp[G_];
            int   off[G_];
            float an_last;
            #pragma unroll
            for (int u = 0; u < G_; ++u) {
                float an = fminf(axv, fminf(ayv, azv));
                bool ok = (an <= end);
                stp[u] = ok ? (an - a_cur) : 0.0f;
                off[u] = off_cur;                 // cell of interval [a_cur, an]
                a_cur = an;
                bool upd = (an < end);            // suppress past/at segment end
                bool cx = (axv == an), cy = (ayv == an), cz = (azv == an);
                kx = cx ? kx + dkx : kx;
                ky = cy ? ky + dky : ky;
                kz = cz ? kz + dkz : kz;
                off_cur += ((cx && upd) ? doffx : 0)
                         + ((cy && upd) ? doffy : 0)
                         + ((cz && upd) ? doffz : 0);
                axv = alpha_mul(kx, spx, sx, inv_dx);  // bitwise-stable recompute
                ayv = alpha_mul(ky, spy, sy, inv_dy);
                azv = alpha_mul(kz, spz, sz, inv_dz);
                an_last = an;
            }
            float v[G_];
            #pragma unroll
            for (int u = 0; u < G_; ++u) v[u] = vol[off[u]];
            #pragma unroll
            for (int u = 0; u < G_; ++u) acc += v[u] * stp[u];
            if (an_last > end) break;
        }
    }
    float result = acc * norm;

    // block-level reduce over the 8 segs of this half, fixed k-order summation
    __shared__ float red[SEGS_PER_BLK * 64];
    red[t] = result;
    __syncthreads();
    if (t < 64) {
        const int ii = ty * TILE_R + (t >> 3);
        const int jj = tx * TILE_C + (t & 7);
        const int opix = b * (H_ * W_) + ii * W_ + jj;
        float s = 0.0f;
        #pragma unroll
        for (int k = 0; k < SEGS_PER_BLK; k++) s += red[t + k * 64];
        partials[(size_t)half * npix + opix] = s;
    }
}

__global__ void __launch_bounds__(256)
drr_combine(const float* __restrict__ partials, float* __restrict__ out, int npix) {
    int pix = blockIdx.x * blockDim.x + threadIdx.x;
    if (pix >= npix) return;
    out[pix] = partials[pix] + partials[(size_t)npix + pix];  // segs 0-7 then 8-15
}

extern "C" void kernel_launch(void* const* d_in, const int* in_sizes, int n_in,
                              void* d_out, int out_size, void* d_ws, size_t ws_size,
                              hipStream_t stream) {
    const float* vol     = (const float*)d_in[0];
    const float* spacing = (const float*)d_in[1];
    const float* sdr     = (const float*)d_in[2];
    const float* rot     = (const float*)d_in[3];
    const float* trans   = (const float*)d_in[4];
    float* out = (float*)d_out;

    const int B = in_sizes[2];
    const int npix = B * H_ * W_;
    float* partials = (float*)d_ws;     // 2 * npix floats

    const int nblocks = B * TILES_PER_IMG * 2;
    drr_partial<<<nblocks, 64 * SEGS_PER_BLK, 0, stream>>>(vol, spacing, sdr, rot, trans, partials, npix);
    drr_combine<<<(npix + 255) / 256, 256, 0, stream>>>(partials, out, npix);
}

// Round 8
// 116.696 us; speedup vs baseline: 1.1445x; 1.0135x over previous
//
#include <hip/hip_runtime.h>

#define H_ 200
#define W_ 200
#define DELX_ 1.5f
#define DELY_ 1.5f
#define NXV_ 256
#define NYV_ 256
#define NZV_ 256
#define EPS_ 1e-8f
#define NSEG 16           // x-slabs of 16 planes each
#define SEGS_PER_BLK 8    // block = 64 px * 8 segs = 512 threads; 2 blocks/tile
#define TILE_R 4          // 4x16 detector patch = 64 px = one wave per seg
#define TILE_C 16         // j (detector s-axis) maps ~0.94 to volume z (fast axis)
#define TROWS (H_ / TILE_R)              // 50
#define TCOLS ((W_ + TILE_C - 1) / TILE_C)  // 13 (padded: last col tile partial)
#define TILES_PER_IMG (TROWS * TCOLS)    // 650
#define G_ 8              // steps marched per group (loads in flight)
#define MAXG 10           // 10 groups * 8 = 80 steps >= worst-case per 16-slab

// alpha for integer plane k, via multiply by precomputed reciprocal (no divide)
__device__ __forceinline__ float alpha_mul(float k, float sp, float src, float inv_sdd) {
    return (k * sp - src) * inv_sdd;
}

__global__ void __launch_bounds__(512, 8)
drr_partial(const float* __restrict__ vol,
            const float* __restrict__ spacing,
            const float* __restrict__ sdr,
            const float* __restrict__ rot,
            const float* __restrict__ trans,
            float* __restrict__ partials,
            int npix) {
    const int t = threadIdx.x;
    const int pixLocal = t & 63;            // 0..63 : 4x16 patch per wave
    const int half = blockIdx.x & 1;        // seg-half of this block
    const int seg = (t >> 6) + (half << 3); // 0..15 ; wave = 64 px x 1 slab
    const int tileBlk = blockIdx.x >> 1;

    const int b    = tileBlk / TILES_PER_IMG;
    const int rem  = tileBlk % TILES_PER_IMG;
    const int ty   = rem / TCOLS;
    const int tx   = rem % TCOLS;
    const int i = ty * TILE_R + (pixLocal >> 4);   // 4 rows
    const int j = tx * TILE_C + (pixLocal & 15);   // 16 cols (may exceed W_-1: padded)

    // --- rotation matrix R = Rz(theta) Ry(phi) Rx(gamma) ---
    const float theta = rot[b * 3 + 0], phi = rot[b * 3 + 1], gamma = rot[b * 3 + 2];
    const float ct = cosf(theta), st = sinf(theta);
    const float cp = cosf(phi),   sp = sinf(phi);
    const float cg = cosf(gamma), sg = sinf(gamma);
    const float r00 = ct * cp,                r10 = st * cp,                r20 = -sp;
    const float r01 = ct * sp * sg - st * cg, r11 = st * sp * sg + ct * cg, r21 = cp * sg;
    const float r02 = ct * sp * cg + st * sg, r12 = st * sp * cg - ct * sg, r22 = cp * cg;

    const float sd = sdr[b];
    const float tx_ = trans[b * 3 + 0], ty_ = trans[b * 3 + 1], tz_ = trans[b * 3 + 2];
    const float sx = sd * r00 + tx_, sy = sd * r10 + ty_, sz = sd * r20 + tz_;
    const float cxx = -sd * r00 + tx_, cyy = -sd * r10 + ty_, czz = -sd * r20 + tz_;

    const float tco = ((float)(i - H_ / 2) + 1.0f) * DELX_;
    const float sco = ((float)(j - W_ / 2) + 1.0f) * DELY_;
    const float gx = r01 * tco + r02 * sco + cxx;
    const float gy = r11 * tco + r12 * sco + cyy;
    const float gz = r21 * tco + r22 * sco + czz;

    const float dx = gx - sx + EPS_;
    const float dy = gy - sy + EPS_;
    const float dz = gz - sz + EPS_;

    const float spx = spacing[0], spy = spacing[1], spz = spacing[2];
    const float inv_spx = 1.0f / spx, inv_spy = 1.0f / spy, inv_spz = 1.0f / spz;
    const float inv_dx = 1.0f / dx, inv_dy = 1.0f / dy, inv_dz = 1.0f / dz;

    const float a0x = alpha_mul(0.f, spx, sx, inv_dx), a1x = alpha_mul((float)NXV_, spx, sx, inv_dx);
    const float a0y = alpha_mul(0.f, spy, sy, inv_dy), a1y = alpha_mul((float)NYV_, spy, sy, inv_dy);
    const float a0z = alpha_mul(0.f, spz, sz, inv_dz), a1z = alpha_mul((float)NZV_, spz, sz, inv_dz);

    const float amin = fmaxf(fmaxf(fminf(a0x, a1x), fminf(a0y, a1y)), fminf(a0z, a1z));
    const float amax = fminf(fminf(fmaxf(a0x, a1x), fmaxf(a0y, a1y)), fmaxf(a0z, a1z));

    const float norm = sqrtf(dx * dx + dy * dy + dz * dz);

    // segment bounds at x-plane crossings (exact members of the crossing set;
    // identical formula across segments -> bitwise-consistent partition)
    const float klo = (float)(seg * (NXV_ / NSEG));
    const float khi = (float)((seg + 1) * (NXV_ / NSEG));
    const float aA = alpha_mul(klo, spx, sx, inv_dx);
    const float aB = alpha_mul(khi, spx, sx, inv_dx);
    const float lo = fminf(aA, aB), hi = fmaxf(aA, aB);

    const float start = fmaxf(amin, lo);
    const float end   = fminf(amax, hi);

    float acc = 0.0f;
    if (start < end) {
        float kx, ky, kz, axv, ayv, azv, dkx, dky, dkz;
        {
            float kf = (start * dx + sx) * inv_spx;
            if (dx > 0.f) { dkx = 1.f;  kx = floorf(kf) + 1.f; }
            else          { dkx = -1.f; kx = ceilf(kf) - 1.f; }
            axv = alpha_mul(kx, spx, sx, inv_dx);
        }
        {
            float kf = (start * dy + sy) * inv_spy;
            if (dy > 0.f) { dky = 1.f;  ky = floorf(kf) + 1.f; }
            else          { dky = -1.f; ky = ceilf(kf) - 1.f; }
            ayv = alpha_mul(ky, spy, sy, inv_dy);
        }
        {
            float kf = (start * dz + sz) * inv_spz;
            if (dz > 0.f) { dkz = 1.f;  kz = floorf(kf) + 1.f; }
            else          { dkz = -1.f; kz = ceilf(kf) - 1.f; }
            azv = alpha_mul(kz, spz, sz, inv_dz);
        }

        // --- incremental cell walk: init cell from first interval midpoint,
        // then bump a single linear offset by the crossed axis's delta.
        // Cell stays in-bounds because updates stop once an >= end (exit-face
        // crossing is suppressed); initial cell clamped once for safety.
        int off_cur;
        {
            float an0 = fminf(axv, fminf(ayv, azv));
            float midv = 0.5f * (start + an0);
            int ix = (int)((sx + midv * dx) * inv_spx);   // trunc, matches ref
            int iy = (int)((sy + midv * dy) * inv_spy);
            int iz = (int)((sz + midv * dz) * inv_spz);
            ix = min(max(ix, 0), NXV_ - 1);
            iy = min(max(iy, 0), NYV_ - 1);
            iz = min(max(iz, 0), NZV_ - 1);
            off_cur = ((NXV_ - 1 - ix) * NYV_ + iy) * NZV_ + iz;  // flip axis 0
        }
        const int doffx = (dkx > 0.f) ? -(NYV_ * NZV_) : (NYV_ * NZV_);  // flipped x
        const int doffy = (dky > 0.f) ? NZV_ : -NZV_;
        const int doffz = (dkz > 0.f) ? 1 : -1;

        float a_cur = start;
        // groups of G_ steps: march G_ (offsets+steps), then G_ loads in flight
        for (int g = 0; g < MAXG; ++g) {
            float stp[G_];
            int   off[G_];
            float an_last;
            #pragma unroll
            for (int u = 0; u < G_; ++u) {
                float an = fminf(axv, fminf(ayv, azv));
                bool ok = (an <= end);
                stp[u] = ok ? (an - a_cur) : 0.0f;
                off[u] = off_cur;                 // cell of interval [a_cur, an]
                a_cur = an;
                bool upd = (an < end);            // suppress past/at segment end
                bool cx = (axv == an), cy = (ayv == an), cz = (azv == an);
                kx = cx ? kx + dkx : kx;
                ky = cy ? ky + dky : ky;
                kz = cz ? kz + dkz : kz;
                off_cur += ((cx && upd) ? doffx : 0)
                         + ((cy && upd) ? doffy : 0)
                         + ((cz && upd) ? doffz : 0);
                axv = alpha_mul(kx, spx, sx, inv_dx);  // bitwise-stable recompute
                ayv = alpha_mul(ky, spy, sy, inv_dy);
                azv = alpha_mul(kz, spz, sz, inv_dz);
                an_last = an;
            }
            float v[G_];
            #pragma unroll
            for (int u = 0; u < G_; ++u) v[u] = vol[off[u]];
            #pragma unroll
            for (int u = 0; u < G_; ++u) acc += v[u] * stp[u];
            if (an_last > end) break;
        }
    }
    float result = acc * norm;

    // block-level reduce over the 8 segs of this half, fixed k-order summation
    __shared__ float red[SEGS_PER_BLK * 64];
    red[t] = result;
    __syncthreads();
    if (t < 64) {
        const int ii = ty * TILE_R + (t >> 4);
        const int jj = tx * TILE_C + (t & 15);
        if (jj < W_) {                          // mask padded columns
            const int opix = b * (H_ * W_) + ii * W_ + jj;
            float s = 0.0f;
            #pragma unroll
            for (int k = 0; k < SEGS_PER_BLK; k++) s += red[t + k * 64];
            partials[(size_t)half * npix + opix] = s;
        }
    }
}

__global__ void __launch_bounds__(256)
drr_combine(const float* __restrict__ partials, float* __restrict__ out, int npix) {
    int pix = blockIdx.x * blockDim.x + threadIdx.x;
    if (pix >= npix) return;
    out[pix] = partials[pix] + partials[(size_t)npix + pix];  // segs 0-7 then 8-15
}

extern "C" void kernel_launch(void* const* d_in, const int* in_sizes, int n_in,
                              void* d_out, int out_size, void* d_ws, size_t ws_size,
                              hipStream_t stream) {
    const float* vol     = (const float*)d_in[0];
    const float* spacing = (const float*)d_in[1];
    const float* sdr     = (const float*)d_in[2];
    const float* rot     = (const float*)d_in[3];
    const float* trans   = (const float*)d_in[4];
    float* out = (float*)d_out;

    const int B = in_sizes[2];
    const int npix = B * H_ * W_;
    float* partials = (float*)d_ws;     // 2 * npix floats

    const int nblocks = B * TILES_PER_IMG * 2;
    drr_partial<<<nblocks, 64 * SEGS_PER_BLK, 0, stream>>>(vol, spacing, sdr, rot, trans, partials, npix);
    drr_combine<<<(npix + 255) / 256, 256, 0, stream>>>(partials, out, npix);
}